// Round 2
// baseline (368.796 us; speedup 1.0000x reference)
//
#include <hip/hip_runtime.h>

// CausalLinearRelativeAttention — chunked 3-branch causal linear attention, bf16 MFMA.
// N=4, L=2048, H=8, D=Dv=128, chunk C=128, T=16 chunks, 3 branches (coeff -2 folded into Qb2).
// R2: vectorized stores everywhere (LDS round-trips), p3 with global-fragment A/V loads,
//     register-Z (intra via shfl, inter fused into k_qfeat), 4 blocks/CU for p3/k_qfeat.

typedef float f32x4 __attribute__((ext_vector_type(4)));
typedef short s16x8 __attribute__((ext_vector_type(8)));
typedef unsigned short u16;

static constexpr int    Ln   = 2048;
static constexpr size_t NHLD = (size_t)32 * 2048 * 128; // per-branch feature elems = 8,388,608
static constexpr size_t KSB  = (size_t)32 * 16 * 128;   // kspre per-branch stride = 65536

__device__ __forceinline__ float b2f(u16 s) {
  union { unsigned u; float f; } x; x.u = ((unsigned)s) << 16; return x.f;
}
__device__ __forceinline__ u16 f2b(float f) {
  union { float f; unsigned u; } x; x.f = f;
  unsigned r = x.u + 0x7fffu + ((x.u >> 16) & 1u);
  return (u16)(r >> 16);
}
__device__ __forceinline__ s16x8 pack8(f32x4 a, f32x4 b) {
  s16x8 r;
  r[0] = (short)f2b(a[0]); r[1] = (short)f2b(a[1]); r[2] = (short)f2b(a[2]); r[3] = (short)f2b(a[3]);
  r[4] = (short)f2b(b[0]); r[5] = (short)f2b(b[1]); r[6] = (short)f2b(b[2]); r[7] = (short)f2b(b[3]);
  return r;
}

// ---------------------------------------------------------------- K0: omega^T (bf16) + column sums
__global__ __launch_bounds__(256) void k_omega(const float* __restrict__ om,
                                               u16* __restrict__ wt, float* __restrict__ osum) {
  __shared__ alignas(16) u16 T[128][136];
  int h = blockIdx.x, t = threadIdx.x;
  for (int idx = t; idx < 128 * 32; idx += 256) {
    int i = idx >> 5, cs = (idx & 31) << 2;
    f32x4 vv = *(const f32x4*)(om + ((size_t)(h * 128 + i)) * 128 + cs);
    T[i][cs + 0] = f2b(vv[0]); T[i][cs + 1] = f2b(vv[1]);
    T[i][cs + 2] = f2b(vv[2]); T[i][cs + 3] = f2b(vv[3]);
  }
  if (t < 128) { // exact fp32 column sums (coalesced per row)
    float acc = 0.f;
    for (int i = 0; i < 128; i++) acc += om[((size_t)(h * 128 + i)) * 128 + t];
    osum[h * 128 + t] = acc;
  }
  __syncthreads();
  { // transposed write: wt[h][j][i] = omega[h][i][j]
    int j = t >> 1, lh = (t & 1) << 6;
    s16x8* dst = (s16x8*)(wt + ((size_t)(h * 128 + j)) * 128 + lh);
    for (int u = 0; u < 8; u++) {
      s16x8 pv;
#pragma unroll
      for (int e = 0; e < 8; e++) pv[e] = (short)T[lh + u * 8 + e][j];
      dst[u] = pv;
    }
  }
}

// ---------------------- K1: K features (natural kb3 + transposed kbt3), V transposed (vt), via LDS
// kb3 b-weights {c^2, s^2, sc}; kb3 stores now vectorized from LDS.
__global__ __launch_bounds__(256) void k_kvfeat(const float* __restrict__ kg, const float* __restrict__ vg,
                                                const float* __restrict__ klg, const float* __restrict__ osum,
                                                u16* __restrict__ kb3, u16* __restrict__ kbt3,
                                                u16* __restrict__ vt) {
  __shared__ alignas(16) u16 Bu[4][32][136]; // Kb0,Kb1,Kb2,V strip tiles
  __shared__ float osb[128];
  int bid = blockIdx.x, t = threadIdx.x;
  int lt = bid & 15, h = (bid >> 4) & 7, n = bid >> 7;
  int l0 = lt << 7, nh = (n << 3) + h;
  const float invL = 1.0f / 2048.0f;
  if (t < 128) osb[t] = osum[h * 128 + t];
  for (int strip = 0; strip < 4; strip++) {
    int ls0 = strip << 5;
    __syncthreads();
    for (int idx = t; idx < 1024; idx += 256) {
      int rr = idx >> 5, cs = (idx & 31) << 2;
      int l = l0 + ls0 + rr;
      size_t gb = (((size_t)(n * Ln + l) * 8 + h) << 7) + cs;
      f32x4 kv = *(const f32x4*)(kg + gb);
      f32x4 vv = *(const f32x4*)(vg + gb);
      float klv = klg[n * Ln + l];
      float tb = (float)l * invL;
#pragma unroll
      for (int e = 0; e < 4; e++) {
        int i = cs + e;
        float kf = (kv[e] > 0.f ? kv[e] + 1.f : __expf(kv[e])) * klv;
        float tt = tb * osb[i];
        float s, c; __sincosf(tt, &s, &c);
        Bu[0][rr][i] = f2b(kf * c * c);
        Bu[1][rr][i] = f2b(kf * s * s);
        Bu[2][rr][i] = f2b(kf * s * c);
        Bu[3][rr][i] = f2b(vv[e]);
      }
    }
    __syncthreads();
    for (int idx = t; idx < 2560; idx += 256) {
      if (idx < 1024) { // transposed stores (kbt3, vt)
        int arr = idx >> 8, rem = idx & 255, i = rem >> 1, hf = rem & 1;
        int lc = hf << 4;
        u16 tmp[16];
#pragma unroll
        for (int u = 0; u < 16; u++) tmp[u] = Bu[arr][lc + u][i];
        u16* dst; size_t db;
        if (arr < 3) { dst = kbt3; db = ((size_t)((arr * 32 + nh) * 128 + i)) * Ln + (l0 + ls0 + lc); }
        else         { dst = vt;   db = ((size_t)(nh * 128 + i)) * Ln + (l0 + ls0 + lc); }
        s16x8 p0, p1;
#pragma unroll
        for (int e = 0; e < 8; e++) { p0[e] = (short)tmp[e]; p1[e] = (short)tmp[8 + e]; }
        *(s16x8*)(dst + db) = p0;
        *(s16x8*)(dst + db + 8) = p1;
      } else {          // natural kb3 stores, vectorized
        int r2 = idx - 1024, arr = r2 >> 9, rem = r2 & 511, rr = rem >> 4, g = (rem & 15) << 3;
        s16x8 pv = *(const s16x8*)&Bu[arr][rr][g];
        *(s16x8*)(kb3 + (size_t)arr * NHLD + ((size_t)nh * Ln + l0 + ls0 + rr) * 128 + g) = pv;
      }
    }
  }
}

// ---------------- P1a: per-chunk S^T[j][i] = sum_s V[s,j]*Kb[s,i]; A/B fragments direct from global
__global__ __launch_bounds__(256, 4) void p1a(const u16* __restrict__ vtg, const u16* __restrict__ kbt3,
                                              u16* __restrict__ sct, float* __restrict__ ksum) {
  __shared__ alignas(16) u16 S[64][136];
  int bid = blockIdx.x, t = threadIdx.x;
  int half = bid & 1, c = (bid >> 1) & 15, h = (bid >> 5) & 7, n = (bid >> 8) & 3, b = bid >> 10;
  int l0 = c << 7, j0 = half << 6, nh = (n << 3) + h, bnh = b * 32 + nh;
  int lane = t & 63, quad = lane >> 4, nl = lane & 15, w = t >> 6;
  f32x4 z4 = {0.f, 0.f, 0.f, 0.f};
  f32x4 acc[8];
#pragma unroll
  for (int i = 0; i < 8; i++) acc[i] = z4;
  int arow = j0 + (w << 4) + nl;
  for (int ks = 0; ks < 4; ks++) {
    int k0 = (ks << 5) + (quad << 3);
    s16x8 av = *(const s16x8*)(vtg + ((size_t)(nh * 128 + arow)) * Ln + l0 + k0);
#pragma unroll
    for (int ct = 0; ct < 8; ct++) {
      s16x8 bv = *(const s16x8*)(kbt3 + ((size_t)(bnh * 128 + (ct << 4) + nl)) * Ln + l0 + k0);
      acc[ct] = __builtin_amdgcn_mfma_f32_16x16x32_bf16(av, bv, acc[ct], 0, 0, 0);
    }
  }
  // C-layout -> LDS -> vector stores
  int lbase = (w << 4) + (quad << 2);
#pragma unroll
  for (int ct = 0; ct < 8; ct++) {
    int i = (ct << 4) + nl;
#pragma unroll
    for (int r = 0; r < 4; r++) S[lbase + r][i] = f2b(acc[ct][r]);
  }
  __syncthreads();
  size_t sbase = ((size_t)(bnh * 16 + c)) << 14;
  for (int idx = t; idx < 1024; idx += 256) {
    int jr = idx >> 4, g = (idx & 15) << 3;
    *(s16x8*)(sct + sbase + ((size_t)(j0 + jr) << 7) + g) = *(const s16x8*)&S[jr][g];
  }
  if (half == 0 && t < 128) { // per-chunk K column sums (rows of kbt3, L1-warm)
    float s = 0.f;
    const u16* kr = kbt3 + ((size_t)(bnh * 128 + t)) * Ln + l0;
    for (int g = 0; g < 16; g++) {
      s16x8 v = *(const s16x8*)(kr + g * 8);
#pragma unroll
      for (int e = 0; e < 8; e++) s += b2f((u16)v[e]);
    }
    ksum[(size_t)(bnh * 16 + c) * 128 + t] = s;
  }
}

// ---------------- P1b: in-place exclusive prefix over chunks, vectorized (s16x8 per thread-chunk)
__global__ __launch_bounds__(256) void p1b(u16* __restrict__ sct, float* __restrict__ ksum) {
  int bid = blockIdx.x, t = threadIdx.x;
  if (bid < 768) {
    int tid = bid * 256 + t;          // 0..196607
    int bnh = tid >> 11, rem = tid & 2047;
    size_t base = ((size_t)bnh << 18) + ((size_t)rem << 3);
    float acc[8] = {0.f, 0.f, 0.f, 0.f, 0.f, 0.f, 0.f, 0.f};
    for (int c = 0; c < 16; c++) {
      size_t a = base + ((size_t)c << 14);
      s16x8 v = *(const s16x8*)(sct + a);
      s16x8 o;
#pragma unroll
      for (int e = 0; e < 8; e++) { o[e] = (short)f2b(acc[e]); acc[e] += b2f((u16)v[e]); }
      *(s16x8*)(sct + a) = o;
    }
  } else {
    int m2 = (bid - 768) * 256 + t;   // 0..12287
    int i = m2 & 127, bnh = m2 >> 7;
    size_t base = (size_t)bnh * 2048 + i;
    float acc = 0.f;
    for (int c = 0; c < 16; c++) {
      size_t a = base + (size_t)c * 128;
      float v = ksum[a];
      ksum[a] = acc;
      acc += v;
    }
  }
}

// ---------------- K2: proj = q2 @ omega (MFMA, A-frags cvt from global fp32), Q features + Z_inter
// qb3 b-weights {s^2, c^2, -2sc}; zint[nh][l] = sum_b <Qb[l], ksum_prefix_b[c(l)]>
__global__ __launch_bounds__(256, 4) void k_qfeat(const float* __restrict__ q2g, const float* __restrict__ qg,
                                                  const u16* __restrict__ wt, const float* __restrict__ osum,
                                                  const float* __restrict__ kspre,
                                                  u16* __restrict__ qb3, float* __restrict__ zintg) {
  __shared__ alignas(16) u16 B[128][136]; // omega^T[h]; later reused rows 0..63 for sin^2(proj)
  __shared__ float osb[128];
  int bid = blockIdx.x, t = threadIdx.x;
  int m = bid & 31, h = (bid >> 5) & 7, n = bid >> 8;
  int l0 = m << 6, c = m >> 1, nh = (n << 3) + h;
  if (t < 128) osb[t] = osum[h * 128 + t];
  for (int idx = t; idx < 2048; idx += 256) {
    int j = idx >> 4, cs = (idx & 15) << 3;
    *(s16x8*)&B[j][cs] = *(const s16x8*)(wt + ((size_t)(h * 128 + j)) * 128 + cs);
  }
  __syncthreads();
  int lane = t & 63, quad = lane >> 4, nl = lane & 15, w = t >> 6;
  f32x4 z4 = {0.f, 0.f, 0.f, 0.f};
  f32x4 acc[8];
#pragma unroll
  for (int i = 0; i < 8; i++) acc[i] = z4;
  int arow = l0 + (w << 4) + nl;
  for (int ks = 0; ks < 4; ks++) {
    int k0 = (ks << 5) + (quad << 3);
    const float* ap = q2g + (((size_t)(n * Ln + arow) * 8 + h) << 7) + k0;
    s16x8 av = pack8(*(const f32x4*)ap, *(const f32x4*)(ap + 4));
#pragma unroll
    for (int ct = 0; ct < 8; ct++) {
      s16x8 bv = *(const s16x8*)&B[(ct << 4) + nl][k0];
      acc[ct] = __builtin_amdgcn_mfma_f32_16x16x32_bf16(av, bv, acc[ct], 0, 0, 0);
    }
  }
  __syncthreads();
  { // sin^2(proj) -> B rows 0..63
    int lbase = (w << 4) + (quad << 2);
#pragma unroll
    for (int ct = 0; ct < 8; ct++) {
      int j = (ct << 4) + nl;
#pragma unroll
      for (int r = 0; r < 4; r++) {
        float sp = __sinf(acc[ct][r]);
        B[lbase + r][j] = f2b(sp * sp);
      }
    }
  }
  __syncthreads();
  const float invL = 1.0f / 2048.0f;
  for (int idx = t; idx < 1024; idx += 256) {
    int l = idx >> 4, j0 = (idx & 15) << 3, gl = l0 + l;
    s16x8 s2v = *(const s16x8*)&B[l][j0];
    const float* qp = qg + (((size_t)(n * Ln + gl) * 8 + h) << 7) + j0;
    f32x4 qa = *(const f32x4*)qp, qbv = *(const f32x4*)(qp + 4);
    size_t kbb = ((size_t)nh * 16 + c) * 128 + j0;
    f32x4 kp0a = *(const f32x4*)(kspre + kbb),           kp0b = *(const f32x4*)(kspre + kbb + 4);
    f32x4 kp1a = *(const f32x4*)(kspre + kbb + KSB),     kp1b = *(const f32x4*)(kspre + kbb + KSB + 4);
    f32x4 kp2a = *(const f32x4*)(kspre + kbb + 2 * KSB), kp2b = *(const f32x4*)(kspre + kbb + 2 * KSB + 4);
    s16x8 o0, o1, o2;
    float z = 0.f;
    float tb = (float)gl * invL;
#pragma unroll
    for (int e = 0; e < 8; e++) {
      float s2p = b2f((u16)s2v[e]);
      float qv = (e < 4) ? qa[e] : qbv[e - 4];
      float f = qv > 0.f ? qv + 1.f : __expf(qv);
      float Qt = s2p * f;
      float tt = tb * osb[j0 + e];
      float s, cc; __sincosf(tt, &s, &cc);
      float v0 = Qt * s * s, v1 = Qt * cc * cc, v2 = -2.f * Qt * s * cc;
      float k0v = (e < 4) ? kp0a[e] : kp0b[e - 4];
      float k1v = (e < 4) ? kp1a[e] : kp1b[e - 4];
      float k2v = (e < 4) ? kp2a[e] : kp2b[e - 4];
      z += v0 * k0v + v1 * k1v + v2 * k2v;
      o0[e] = (short)f2b(v0); o1[e] = (short)f2b(v1); o2[e] = (short)f2b(v2);
    }
    size_t base = ((size_t)nh * Ln + gl) * 128 + j0;
    *(s16x8*)(qb3 + base)            = o0;
    *(s16x8*)(qb3 + base + NHLD)     = o1;
    *(s16x8*)(qb3 + base + 2 * NHLD) = o2;
    z += __shfl_xor(z, 1); z += __shfl_xor(z, 2);
    z += __shfl_xor(z, 4); z += __shfl_xor(z, 8);
    if (nl == 0) zintg[(size_t)nh * Ln + gl] = z;
  }
}

// ---------------- P3: P-scores + causal mask + intra PV + inter Q*Sprefix, register Z, divide
__global__ __launch_bounds__(256, 4) void p3(const u16* __restrict__ qb3, const u16* __restrict__ kb3,
                                             const u16* __restrict__ vtg, const u16* __restrict__ sct,
                                             const float* __restrict__ zintg, float* __restrict__ outg) {
  __shared__ alignas(16) u16 B[128][136]; // Kb / Sprefix^T staging; rows 0..63 reused for masked P
  int bid = blockIdx.x, t = threadIdx.x;
  int half = bid & 1, c = (bid >> 1) & 15, h = (bid >> 5) & 7, n = bid >> 8;
  int l0c = c << 7, l0 = l0c + (half << 6), nh = (n << 3) + h;
  int lane = t & 63, quad = lane >> 4, nl = lane & 15, w = t >> 6;
  f32x4 z4 = {0.f, 0.f, 0.f, 0.f};
  f32x4 accP[8], accO[8];
#pragma unroll
  for (int i = 0; i < 8; i++) { accP[i] = z4; accO[i] = z4; }
  int arow = l0 + (w << 4) + nl;
  for (int b = 0; b < 3; b++) {
    int bnh = b * 32 + nh;
    __syncthreads();
    for (int idx = t; idx < 2048; idx += 256) { // B <- Kb chunk
      int s = idx >> 4, cs = (idx & 15) << 3;
      *(s16x8*)&B[s][cs] = *(const s16x8*)(kb3 + (((size_t)bnh * Ln + l0c + s) << 7) + cs);
    }
    __syncthreads();
    s16x8 av[4];
#pragma unroll
    for (int ks = 0; ks < 4; ks++)
      av[ks] = *(const s16x8*)(qb3 + (((size_t)bnh * Ln + arow) << 7) + (ks << 5) + (quad << 3));
    for (int ks = 0; ks < 4; ks++) {
      int k0 = (ks << 5) + (quad << 3);
#pragma unroll
      for (int ct = 0; ct < 8; ct++) {
        s16x8 bv = *(const s16x8*)&B[(ct << 4) + nl][k0];
        accP[ct] = __builtin_amdgcn_mfma_f32_16x16x32_bf16(av[ks], bv, accP[ct], 0, 0, 0);
      }
    }
    __syncthreads();
    size_t sbase = ((size_t)(bnh * 16 + c)) << 14;
    for (int idx = t; idx < 2048; idx += 256) { // B <- Sprefix^T
      int j = idx >> 4, cs = (idx & 15) << 3;
      *(s16x8*)&B[j][cs] = *(const s16x8*)(sct + sbase + ((size_t)j << 7) + cs);
    }
    __syncthreads();
    for (int ks = 0; ks < 4; ks++) {
      int k0 = (ks << 5) + (quad << 3);
#pragma unroll
      for (int ct = 0; ct < 8; ct++) {
        s16x8 bv = *(const s16x8*)&B[(ct << 4) + nl][k0];
        accO[ct] = __builtin_amdgcn_mfma_f32_16x16x32_bf16(av[ks], bv, accO[ct], 0, 0, 0);
      }
    }
  }
  __syncthreads();
  // masked P -> B rows 0..63 (bf16) + register row-sums (Z_intra)
  float zP[4] = {0.f, 0.f, 0.f, 0.f};
  int lbase = (w << 4) + (quad << 2);
#pragma unroll
  for (int ct = 0; ct < 8; ct++) {
    int ss = (ct << 4) + nl;
#pragma unroll
    for (int r = 0; r < 4; r++) {
      int lr = lbase + r;
      float pv = (ss <= (half << 6) + lr) ? accP[ct][r] : 0.f;
      zP[r] += pv;
      B[lr][ss] = f2b(pv);
    }
  }
#pragma unroll
  for (int mteam = 1; mteam <= 8; mteam <<= 1) {
#pragma unroll
    for (int r = 0; r < 4; r++) zP[r] += __shfl_xor(zP[r], mteam);
  }
  __syncthreads();
  // intra: A = masked P (LDS), B = V^T fragments direct from global
  for (int ks = 0; ks < 4; ks++) {
    int k0 = (ks << 5) + (quad << 3);
    s16x8 pav = *(const s16x8*)&B[(w << 4) + nl][k0];
#pragma unroll
    for (int ct = 0; ct < 8; ct++) {
      s16x8 vv = *(const s16x8*)(vtg + ((size_t)(nh * 128 + (ct << 4) + nl)) * Ln + l0c + k0);
      accO[ct] = __builtin_amdgcn_mfma_f32_16x16x32_bf16(pav, vv, accO[ct], 0, 0, 0);
    }
  }
  float zf[4];
#pragma unroll
  for (int r = 0; r < 4; r++)
    zf[r] = zintg[(size_t)nh * Ln + l0 + lbase + r] + zP[r] + 1e-6f;
#pragma unroll
  for (int ct = 0; ct < 8; ct++) {
    int j = (ct << 4) + nl;
#pragma unroll
    for (int r = 0; r < 4; r++) {
      int lr = lbase + r;
      outg[(((size_t)n * Ln + (l0 + lr)) * 8 + h) * 128 + j] = accO[ct][r] / zf[r];
    }
  }
}

extern "C" void kernel_launch(void* const* d_in, const int* in_sizes, int n_in,
                              void* d_out, int out_size, void* d_ws, size_t ws_size,
                              hipStream_t stream) {
  (void)in_sizes; (void)n_in; (void)out_size; (void)ws_size;
  const float* q   = (const float*)d_in[0];
  const float* q2  = (const float*)d_in[1];
  const float* kk  = (const float*)d_in[2];
  const float* vv  = (const float*)d_in[3];
  const float* kl  = (const float*)d_in[4];
  const float* om  = (const float*)d_in[5];
  float* out = (float*)d_out;

  // workspace carve (bf16 region then fp32 region) — ~219 MB
  u16* W     = (u16*)d_ws;
  u16* qb3   = W;                 // 3*NHLD
  u16* kb3   = W + 3 * NHLD;      // 3*NHLD
  u16* kbt3  = W + 6 * NHLD;      // 3*NHLD
  u16* vt    = W + 9 * NHLD;      // NHLD
  u16* sct   = W + 10 * NHLD;     // 3*NHLD (chunk sums -> exclusive prefix, in place)
  u16* wt    = W + 13 * NHLD;     // 131072 (omega^T bf16)
  float* ks  = (float*)(W + 13 * NHLD + 131072); // 196608 f32 (chunk Ksum -> prefix)
  float* osm = ks + 196608;       // 1024 f32
  float* zin = osm + 1024;        // 65536 f32 (Z_inter)

  k_omega <<<8,    256, 0, stream>>>(om, wt, osm);
  k_kvfeat<<<512,  256, 0, stream>>>(kk, vv, kl, osm, kb3, kbt3, vt);
  p1a     <<<3072, 256, 0, stream>>>(vt, kbt3, sct, ks);
  p1b     <<<816,  256, 0, stream>>>(sct, ks);
  k_qfeat <<<1024, 256, 0, stream>>>(q2, q, wt, osm, ks, qb3, zin);
  p3      <<<1024, 256, 0, stream>>>(qb3, kb3, vt, sct, zin, out);
}

// Round 3
// 292.974 us; speedup vs baseline: 1.2588x; 1.2588x over previous
//
#include <hip/hip_runtime.h>

// CausalLinearRelativeAttention — chunked 3-branch causal linear attention, bf16 MFMA.
// N=4, L=2048, H=8, D=Dv=128, chunk C=128, T=16 chunks, 3 branches (coeff -2 folded into Qb2).
// R3: p3 full-chunk blocks (512 thr) + full-line output via LDS fp32 tile; p1a restored LDS
//     B-staging with full-j blocks; vectorized stores everywhere.

typedef float f32x4 __attribute__((ext_vector_type(4)));
typedef short s16x8 __attribute__((ext_vector_type(8)));
typedef unsigned short u16;

static constexpr int    Ln   = 2048;
static constexpr size_t NHLD = (size_t)32 * 2048 * 128; // per-branch feature elems = 8,388,608
static constexpr size_t KSB  = (size_t)32 * 16 * 128;   // kspre per-branch stride = 65536

__device__ __forceinline__ float b2f(u16 s) {
  union { unsigned u; float f; } x; x.u = ((unsigned)s) << 16; return x.f;
}
__device__ __forceinline__ u16 f2b(float f) {
  union { float f; unsigned u; } x; x.f = f;
  unsigned r = x.u + 0x7fffu + ((x.u >> 16) & 1u);
  return (u16)(r >> 16);
}
__device__ __forceinline__ s16x8 pack8(f32x4 a, f32x4 b) {
  s16x8 r;
  r[0] = (short)f2b(a[0]); r[1] = (short)f2b(a[1]); r[2] = (short)f2b(a[2]); r[3] = (short)f2b(a[3]);
  r[4] = (short)f2b(b[0]); r[5] = (short)f2b(b[1]); r[6] = (short)f2b(b[2]); r[7] = (short)f2b(b[3]);
  return r;
}

// ---------------------------------------------------------------- K0: omega^T (bf16) + column sums
__global__ __launch_bounds__(256) void k_omega(const float* __restrict__ om,
                                               u16* __restrict__ wt, float* __restrict__ osum) {
  __shared__ alignas(16) u16 T[128][136];
  int h = blockIdx.x, t = threadIdx.x;
  for (int idx = t; idx < 128 * 32; idx += 256) {
    int i = idx >> 5, cs = (idx & 31) << 2;
    f32x4 vv = *(const f32x4*)(om + ((size_t)(h * 128 + i)) * 128 + cs);
    T[i][cs + 0] = f2b(vv[0]); T[i][cs + 1] = f2b(vv[1]);
    T[i][cs + 2] = f2b(vv[2]); T[i][cs + 3] = f2b(vv[3]);
  }
  if (t < 128) { // exact fp32 column sums (coalesced per row)
    float acc = 0.f;
    for (int i = 0; i < 128; i++) acc += om[((size_t)(h * 128 + i)) * 128 + t];
    osum[h * 128 + t] = acc;
  }
  __syncthreads();
  { // transposed write: wt[h][j][i] = omega[h][i][j]
    int j = t >> 1, lh = (t & 1) << 6;
    s16x8* dst = (s16x8*)(wt + ((size_t)(h * 128 + j)) * 128 + lh);
    for (int u = 0; u < 8; u++) {
      s16x8 pv;
#pragma unroll
      for (int e = 0; e < 8; e++) pv[e] = (short)T[lh + u * 8 + e][j];
      dst[u] = pv;
    }
  }
}

// ---------------------- K1: K features (natural kb3 + transposed kbt3), V transposed (vt), via LDS
// kb3 b-weights {c^2, s^2, sc}
__global__ __launch_bounds__(256) void k_kvfeat(const float* __restrict__ kg, const float* __restrict__ vg,
                                                const float* __restrict__ klg, const float* __restrict__ osum,
                                                u16* __restrict__ kb3, u16* __restrict__ kbt3,
                                                u16* __restrict__ vt) {
  __shared__ alignas(16) u16 Bu[4][32][136]; // Kb0,Kb1,Kb2,V strip tiles
  __shared__ float osb[128];
  int bid = blockIdx.x, t = threadIdx.x;
  int lt = bid & 15, h = (bid >> 4) & 7, n = bid >> 7;
  int l0 = lt << 7, nh = (n << 3) + h;
  const float invL = 1.0f / 2048.0f;
  if (t < 128) osb[t] = osum[h * 128 + t];
  for (int strip = 0; strip < 4; strip++) {
    int ls0 = strip << 5;
    __syncthreads();
    for (int idx = t; idx < 1024; idx += 256) {
      int rr = idx >> 5, cs = (idx & 31) << 2;
      int l = l0 + ls0 + rr;
      size_t gb = (((size_t)(n * Ln + l) * 8 + h) << 7) + cs;
      f32x4 kv = *(const f32x4*)(kg + gb);
      f32x4 vv = *(const f32x4*)(vg + gb);
      float klv = klg[n * Ln + l];
      float tb = (float)l * invL;
#pragma unroll
      for (int e = 0; e < 4; e++) {
        int i = cs + e;
        float kf = (kv[e] > 0.f ? kv[e] + 1.f : __expf(kv[e])) * klv;
        float tt = tb * osb[i];
        float s, c; __sincosf(tt, &s, &c);
        Bu[0][rr][i] = f2b(kf * c * c);
        Bu[1][rr][i] = f2b(kf * s * s);
        Bu[2][rr][i] = f2b(kf * s * c);
        Bu[3][rr][i] = f2b(vv[e]);
      }
    }
    __syncthreads();
    for (int idx = t; idx < 2560; idx += 256) {
      if (idx < 1024) { // transposed stores (kbt3, vt)
        int arr = idx >> 8, rem = idx & 255, i = rem >> 1, hf = rem & 1;
        int lc = hf << 4;
        u16 tmp[16];
#pragma unroll
        for (int u = 0; u < 16; u++) tmp[u] = Bu[arr][lc + u][i];
        u16* dst; size_t db;
        if (arr < 3) { dst = kbt3; db = ((size_t)((arr * 32 + nh) * 128 + i)) * Ln + (l0 + ls0 + lc); }
        else         { dst = vt;   db = ((size_t)(nh * 128 + i)) * Ln + (l0 + ls0 + lc); }
        s16x8 p0, p1;
#pragma unroll
        for (int e = 0; e < 8; e++) { p0[e] = (short)tmp[e]; p1[e] = (short)tmp[8 + e]; }
        *(s16x8*)(dst + db) = p0;
        *(s16x8*)(dst + db + 8) = p1;
      } else {          // natural kb3 stores, vectorized
        int r2 = idx - 1024, arr = r2 >> 9, rem = r2 & 511, rr = rem >> 4, g = (rem & 15) << 3;
        s16x8 pv = *(const s16x8*)&Bu[arr][rr][g];
        *(s16x8*)(kb3 + (size_t)arr * NHLD + ((size_t)nh * Ln + l0 + ls0 + rr) * 128 + g) = pv;
      }
    }
  }
}

// ---------------- P1a: per-chunk S^T[j][i] = sum_s V[s,j]*Kb[s,i]; B staged in LDS once per block
__global__ __launch_bounds__(512, 4) void p1a(const u16* __restrict__ vtg, const u16* __restrict__ kbt3,
                                              u16* __restrict__ sct, float* __restrict__ ksum) {
  __shared__ alignas(16) u16 B[128][136]; // kbt3 chunk [i][s], later reused for S^T staging
  int bid = blockIdx.x, t = threadIdx.x;
  int c = bid & 15, h = (bid >> 4) & 7, n = (bid >> 7) & 3, b = bid >> 9;
  int l0 = c << 7, nh = (n << 3) + h, bnh = b * 32 + nh;
  int lane = t & 63, quad = lane >> 4, nl = lane & 15, w = t >> 6;
  for (int idx = t; idx < 2048; idx += 512) {
    int i = idx >> 4, cs = (idx & 15) << 3;
    *(s16x8*)&B[i][cs] = *(const s16x8*)(kbt3 + ((size_t)(bnh * 128 + i)) * Ln + l0 + cs);
  }
  __syncthreads();
  f32x4 z4 = {0.f, 0.f, 0.f, 0.f};
  f32x4 acc[8];
#pragma unroll
  for (int i = 0; i < 8; i++) acc[i] = z4;
  int arow = (w << 4) + nl; // j row, 8 waves x 16 = 128
  for (int ks = 0; ks < 4; ks++) {
    int k0 = (ks << 5) + (quad << 3);
    s16x8 av = *(const s16x8*)(vtg + ((size_t)(nh * 128 + arow)) * Ln + l0 + k0);
#pragma unroll
    for (int ct = 0; ct < 8; ct++) {
      s16x8 bv = *(const s16x8*)&B[(ct << 4) + nl][k0];
      acc[ct] = __builtin_amdgcn_mfma_f32_16x16x32_bf16(av, bv, acc[ct], 0, 0, 0);
    }
  }
  if (t < 128) { // ksum[i] = row-sum of kbt3 row i (before B is overwritten)
    float s = 0.f;
#pragma unroll 4
    for (int g = 0; g < 128; g += 8) {
      s16x8 v = *(const s16x8*)&B[t][g];
#pragma unroll
      for (int e = 0; e < 8; e++) s += b2f((u16)v[e]);
    }
    ksum[(size_t)(bnh * 16 + c) * 128 + t] = s;
  }
  __syncthreads();
  { // C-layout -> B (as S^T[j][i])
    int lbase = (w << 4) + (quad << 2);
#pragma unroll
    for (int ct = 0; ct < 8; ct++) {
      int i = (ct << 4) + nl;
#pragma unroll
      for (int r = 0; r < 4; r++) B[lbase + r][i] = f2b(acc[ct][r]);
    }
  }
  __syncthreads();
  size_t sbase = ((size_t)(bnh * 16 + c)) << 14;
  for (int idx = t; idx < 2048; idx += 512) {
    int jr = idx >> 4, g = (idx & 15) << 3;
    *(s16x8*)(sct + sbase + ((size_t)jr << 7) + g) = *(const s16x8*)&B[jr][g];
  }
}

// ---------------- P1b: in-place exclusive prefix over chunks, vectorized
__global__ __launch_bounds__(256) void p1b(u16* __restrict__ sct, float* __restrict__ ksum) {
  int bid = blockIdx.x, t = threadIdx.x;
  if (bid < 768) {
    int tid = bid * 256 + t;          // 0..196607
    int bnh = tid >> 11, rem = tid & 2047;
    size_t base = ((size_t)bnh << 18) + ((size_t)rem << 3);
    float acc[8] = {0.f, 0.f, 0.f, 0.f, 0.f, 0.f, 0.f, 0.f};
    for (int c = 0; c < 16; c++) {
      size_t a = base + ((size_t)c << 14);
      s16x8 v = *(const s16x8*)(sct + a);
      s16x8 o;
#pragma unroll
      for (int e = 0; e < 8; e++) { o[e] = (short)f2b(acc[e]); acc[e] += b2f((u16)v[e]); }
      *(s16x8*)(sct + a) = o;
    }
  } else {
    int m2 = (bid - 768) * 256 + t;   // 0..12287
    int i = m2 & 127, bnh = m2 >> 7;
    size_t base = (size_t)bnh * 2048 + i;
    float acc = 0.f;
    for (int c = 0; c < 16; c++) {
      size_t a = base + (size_t)c * 128;
      float v = ksum[a];
      ksum[a] = acc;
      acc += v;
    }
  }
}

// ---------------- K2: proj = q2 @ omega (MFMA), Q features + Z_inter fused
// qb3 b-weights {s^2, c^2, -2sc}; zint[nh][l] = sum_b <Qb[l], ksum_prefix_b[c(l)]>
__global__ __launch_bounds__(256, 2) void k_qfeat(const float* __restrict__ q2g, const float* __restrict__ qg,
                                                  const u16* __restrict__ wt, const float* __restrict__ osum,
                                                  const float* __restrict__ kspre,
                                                  u16* __restrict__ qb3, float* __restrict__ zintg) {
  __shared__ alignas(16) u16 B[128][136]; // omega^T[h]; later reused rows 0..63 for sin^2(proj)
  __shared__ float osb[128];
  int bid = blockIdx.x, t = threadIdx.x;
  int m = bid & 31, h = (bid >> 5) & 7, n = bid >> 8;
  int l0 = m << 6, c = m >> 1, nh = (n << 3) + h;
  if (t < 128) osb[t] = osum[h * 128 + t];
  for (int idx = t; idx < 2048; idx += 256) {
    int j = idx >> 4, cs = (idx & 15) << 3;
    *(s16x8*)&B[j][cs] = *(const s16x8*)(wt + ((size_t)(h * 128 + j)) * 128 + cs);
  }
  __syncthreads();
  int lane = t & 63, quad = lane >> 4, nl = lane & 15, w = t >> 6;
  f32x4 z4 = {0.f, 0.f, 0.f, 0.f};
  f32x4 acc[8];
#pragma unroll
  for (int i = 0; i < 8; i++) acc[i] = z4;
  int arow = l0 + (w << 4) + nl;
  for (int ks = 0; ks < 4; ks++) {
    int k0 = (ks << 5) + (quad << 3);
    const float* ap = q2g + (((size_t)(n * Ln + arow) * 8 + h) << 7) + k0;
    s16x8 av = pack8(*(const f32x4*)ap, *(const f32x4*)(ap + 4));
#pragma unroll
    for (int ct = 0; ct < 8; ct++) {
      s16x8 bv = *(const s16x8*)&B[(ct << 4) + nl][k0];
      acc[ct] = __builtin_amdgcn_mfma_f32_16x16x32_bf16(av, bv, acc[ct], 0, 0, 0);
    }
  }
  __syncthreads();
  { // sin^2(proj) -> B rows 0..63
    int lbase = (w << 4) + (quad << 2);
#pragma unroll
    for (int ct = 0; ct < 8; ct++) {
      int j = (ct << 4) + nl;
#pragma unroll
      for (int r = 0; r < 4; r++) {
        float sp = __sinf(acc[ct][r]);
        B[lbase + r][j] = f2b(sp * sp);
      }
    }
  }
  __syncthreads();
  const float invL = 1.0f / 2048.0f;
  for (int idx = t; idx < 1024; idx += 256) {
    int l = idx >> 4, j0 = (idx & 15) << 3, gl = l0 + l;
    s16x8 s2v = *(const s16x8*)&B[l][j0];
    const float* qp = qg + (((size_t)(n * Ln + gl) * 8 + h) << 7) + j0;
    f32x4 qa = *(const f32x4*)qp, qbv = *(const f32x4*)(qp + 4);
    size_t kbb = ((size_t)nh * 16 + c) * 128 + j0;
    f32x4 kp0a = *(const f32x4*)(kspre + kbb),           kp0b = *(const f32x4*)(kspre + kbb + 4);
    f32x4 kp1a = *(const f32x4*)(kspre + kbb + KSB),     kp1b = *(const f32x4*)(kspre + kbb + KSB + 4);
    f32x4 kp2a = *(const f32x4*)(kspre + kbb + 2 * KSB), kp2b = *(const f32x4*)(kspre + kbb + 2 * KSB + 4);
    s16x8 o0, o1, o2;
    float z = 0.f;
    float tb = (float)gl * invL;
#pragma unroll
    for (int e = 0; e < 8; e++) {
      float s2p = b2f((u16)s2v[e]);
      float qv = (e < 4) ? qa[e] : qbv[e - 4];
      float f = qv > 0.f ? qv + 1.f : __expf(qv);
      float Qt = s2p * f;
      float tt = tb * osb[j0 + e];
      float s, cc; __sincosf(tt, &s, &cc);
      float v0 = Qt * s * s, v1 = Qt * cc * cc, v2 = -2.f * Qt * s * cc;
      float k0v = (e < 4) ? kp0a[e] : kp0b[e - 4];
      float k1v = (e < 4) ? kp1a[e] : kp1b[e - 4];
      float k2v = (e < 4) ? kp2a[e] : kp2b[e - 4];
      z += v0 * k0v + v1 * k1v + v2 * k2v;
      o0[e] = (short)f2b(v0); o1[e] = (short)f2b(v1); o2[e] = (short)f2b(v2);
    }
    size_t base = ((size_t)nh * Ln + gl) * 128 + j0;
    *(s16x8*)(qb3 + base)            = o0;
    *(s16x8*)(qb3 + base + NHLD)     = o1;
    *(s16x8*)(qb3 + base + 2 * NHLD) = o2;
    z += __shfl_xor(z, 1); z += __shfl_xor(z, 2);
    z += __shfl_xor(z, 4); z += __shfl_xor(z, 8);
    if (nl == 0) zintg[(size_t)nh * Ln + gl] = z;
  }
}

// ---------------- P3: full-chunk blocks. P-scores + mask + intra PV + inter Q*Sprefix, reg Z,
//                  full-line fp32 output via LDS overlay.
__global__ __launch_bounds__(512, 4) void p3(const u16* __restrict__ qb3, const u16* __restrict__ kb3,
                                             const u16* __restrict__ vtg, const u16* __restrict__ sct,
                                             const float* __restrict__ zintg, float* __restrict__ outg) {
  __shared__ union {
    struct { alignas(16) u16 B[128][136]; alignas(16) u16 P[128][136]; } s;
    alignas(16) float O[128][132];
  } sm;
  int bid = blockIdx.x, t = threadIdx.x;
  int c = bid & 15, h = (bid >> 4) & 7, n = bid >> 7;
  int l0c = c << 7, nh = (n << 3) + h;
  int lane = t & 63, quad = lane >> 4, nl = lane & 15, w = t >> 6;
  f32x4 z4 = {0.f, 0.f, 0.f, 0.f};
  f32x4 accP[8], accO[8];
#pragma unroll
  for (int i = 0; i < 8; i++) { accP[i] = z4; accO[i] = z4; }
  int arow = l0c + (w << 4) + nl;
  for (int b = 0; b < 3; b++) {
    int bnh = b * 32 + nh;
    __syncthreads();
    for (int idx = t; idx < 2048; idx += 512) { // B <- Kb chunk [s][i]
      int s = idx >> 4, cs = (idx & 15) << 3;
      *(s16x8*)&sm.s.B[s][cs] = *(const s16x8*)(kb3 + (((size_t)bnh * Ln + l0c + s) << 7) + cs);
    }
    __syncthreads();
    s16x8 av[4];
#pragma unroll
    for (int ks = 0; ks < 4; ks++)
      av[ks] = *(const s16x8*)(qb3 + (((size_t)bnh * Ln + arow) << 7) + (ks << 5) + (quad << 3));
    for (int ks = 0; ks < 4; ks++) {
      int k0 = (ks << 5) + (quad << 3);
#pragma unroll
      for (int ct = 0; ct < 8; ct++) {
        s16x8 bv = *(const s16x8*)&sm.s.B[(ct << 4) + nl][k0];
        accP[ct] = __builtin_amdgcn_mfma_f32_16x16x32_bf16(av[ks], bv, accP[ct], 0, 0, 0);
      }
    }
    __syncthreads();
    size_t sbase = ((size_t)(bnh * 16 + c)) << 14;
    for (int idx = t; idx < 2048; idx += 512) { // B <- Sprefix^T [j][i]
      int j = idx >> 4, cs = (idx & 15) << 3;
      *(s16x8*)&sm.s.B[j][cs] = *(const s16x8*)(sct + sbase + ((size_t)j << 7) + cs);
    }
    __syncthreads();
    for (int ks = 0; ks < 4; ks++) {
      int k0 = (ks << 5) + (quad << 3);
#pragma unroll
      for (int ct = 0; ct < 8; ct++) {
        s16x8 bv = *(const s16x8*)&sm.s.B[(ct << 4) + nl][k0];
        accO[ct] = __builtin_amdgcn_mfma_f32_16x16x32_bf16(av[ks], bv, accO[ct], 0, 0, 0);
      }
    }
  }
  __syncthreads();
  // masked P -> sm.s.P (bf16) + register row-sums; stage V^T -> sm.s.B
  float zP[4] = {0.f, 0.f, 0.f, 0.f};
  int lbase = (w << 4) + (quad << 2);
#pragma unroll
  for (int ct = 0; ct < 8; ct++) {
    int ss = (ct << 4) + nl;
#pragma unroll
    for (int r = 0; r < 4; r++) {
      int lr = lbase + r;
      float pv = (ss <= lr) ? accP[ct][r] : 0.f;
      zP[r] += pv;
      sm.s.P[lr][ss] = f2b(pv);
    }
  }
#pragma unroll
  for (int mteam = 1; mteam <= 8; mteam <<= 1) {
#pragma unroll
    for (int r = 0; r < 4; r++) zP[r] += __shfl_xor(zP[r], mteam);
  }
  for (int idx = t; idx < 2048; idx += 512) { // B <- V^T [j][s]
    int j = idx >> 4, cs = (idx & 15) << 3;
    *(s16x8*)&sm.s.B[j][cs] = *(const s16x8*)(vtg + ((size_t)(nh * 128 + j)) * Ln + l0c + cs);
  }
  float zf[4];
#pragma unroll
  for (int r = 0; r < 4; r++)
    zf[r] = zintg[(size_t)nh * Ln + l0c + lbase + r] + zP[r] + 1e-6f;
  __syncthreads();
  // intra: A = masked P (LDS), B = V^T (LDS)
  for (int ks = 0; ks < 4; ks++) {
    int k0 = (ks << 5) + (quad << 3);
    s16x8 pav = *(const s16x8*)&sm.s.P[(w << 4) + nl][k0];
#pragma unroll
    for (int ct = 0; ct < 8; ct++) {
      s16x8 vv = *(const s16x8*)&sm.s.B[(ct << 4) + nl][k0];
      accO[ct] = __builtin_amdgcn_mfma_f32_16x16x32_bf16(pav, vv, accO[ct], 0, 0, 0);
    }
  }
  __syncthreads();
  // divided result -> fp32 LDS overlay (B/P dead now)
#pragma unroll
  for (int ct = 0; ct < 8; ct++) {
    int j = (ct << 4) + nl;
#pragma unroll
    for (int r = 0; r < 4; r++) sm.O[lbase + r][j] = accO[ct][r] / zf[r];
  }
  __syncthreads();
  for (int idx = t; idx < 4096; idx += 512) { // full 512B-row coalesced stores
    int l = idx >> 5, g = (idx & 31) << 2;
    *(f32x4*)(outg + (((size_t)(n * Ln + l0c + l) * 8 + h) << 7) + g) = *(const f32x4*)&sm.O[l][g];
  }
}

extern "C" void kernel_launch(void* const* d_in, const int* in_sizes, int n_in,
                              void* d_out, int out_size, void* d_ws, size_t ws_size,
                              hipStream_t stream) {
  (void)in_sizes; (void)n_in; (void)out_size; (void)ws_size;
  const float* q   = (const float*)d_in[0];
  const float* q2  = (const float*)d_in[1];
  const float* kk  = (const float*)d_in[2];
  const float* vv  = (const float*)d_in[3];
  const float* kl  = (const float*)d_in[4];
  const float* om  = (const float*)d_in[5];
  float* out = (float*)d_out;

  // workspace carve (bf16 region then fp32 region) — ~219 MB
  u16* W     = (u16*)d_ws;
  u16* qb3   = W;                 // 3*NHLD
  u16* kb3   = W + 3 * NHLD;      // 3*NHLD
  u16* kbt3  = W + 6 * NHLD;      // 3*NHLD
  u16* vt    = W + 9 * NHLD;      // NHLD
  u16* sct   = W + 10 * NHLD;     // 3*NHLD (chunk sums -> exclusive prefix, in place)
  u16* wt    = W + 13 * NHLD;     // 131072 (omega^T bf16)
  float* ks  = (float*)(W + 13 * NHLD + 131072); // 196608 f32 (chunk Ksum -> prefix)
  float* osm = ks + 196608;       // 1024 f32
  float* zin = osm + 1024;        // 65536 f32 (Z_inter)

  k_omega <<<8,    256, 0, stream>>>(om, wt, osm);
  k_kvfeat<<<512,  256, 0, stream>>>(kk, vv, kl, osm, kb3, kbt3, vt);
  p1a     <<<1536, 512, 0, stream>>>(vt, kbt3, sct, ks);
  p1b     <<<816,  256, 0, stream>>>(sct, ks);
  k_qfeat <<<1024, 256, 0, stream>>>(q2, q, wt, osm, ks, qb3, zin);
  p3      <<<512,  512, 0, stream>>>(qb3, kb3, vt, sct, zin, out);
}

// Round 4
// 290.091 us; speedup vs baseline: 1.2713x; 1.0099x over previous
//
#include <hip/hip_runtime.h>

// CausalLinearRelativeAttention — chunked 3-branch causal linear attention, bf16 MFMA.
// N=4, L=2048, H=8, D=Dv=128, chunk C=128, T=16 chunks, 3 branches (coeff -2 folded into Qb2).
// R4: k_kvfeat one-strip-per-block (grid 2048, 2 barriers); p3 double-tile staging (T0/T1).

typedef float f32x4 __attribute__((ext_vector_type(4)));
typedef short s16x8 __attribute__((ext_vector_type(8)));
typedef unsigned short u16;

static constexpr int    Ln   = 2048;
static constexpr size_t NHLD = (size_t)32 * 2048 * 128; // per-branch feature elems = 8,388,608
static constexpr size_t KSB  = (size_t)32 * 16 * 128;   // kspre per-branch stride = 65536

__device__ __forceinline__ float b2f(u16 s) {
  union { unsigned u; float f; } x; x.u = ((unsigned)s) << 16; return x.f;
}
__device__ __forceinline__ u16 f2b(float f) {
  union { float f; unsigned u; } x; x.f = f;
  unsigned r = x.u + 0x7fffu + ((x.u >> 16) & 1u);
  return (u16)(r >> 16);
}
__device__ __forceinline__ s16x8 pack8(f32x4 a, f32x4 b) {
  s16x8 r;
  r[0] = (short)f2b(a[0]); r[1] = (short)f2b(a[1]); r[2] = (short)f2b(a[2]); r[3] = (short)f2b(a[3]);
  r[4] = (short)f2b(b[0]); r[5] = (short)f2b(b[1]); r[6] = (short)f2b(b[2]); r[7] = (short)f2b(b[3]);
  return r;
}

// ---------------------------------------------------------------- K0: omega^T (bf16) + column sums
__global__ __launch_bounds__(256) void k_omega(const float* __restrict__ om,
                                               u16* __restrict__ wt, float* __restrict__ osum) {
  __shared__ alignas(16) u16 T[128][136];
  int h = blockIdx.x, t = threadIdx.x;
  for (int idx = t; idx < 128 * 32; idx += 256) {
    int i = idx >> 5, cs = (idx & 31) << 2;
    f32x4 vv = *(const f32x4*)(om + ((size_t)(h * 128 + i)) * 128 + cs);
    T[i][cs + 0] = f2b(vv[0]); T[i][cs + 1] = f2b(vv[1]);
    T[i][cs + 2] = f2b(vv[2]); T[i][cs + 3] = f2b(vv[3]);
  }
  if (t < 128) { // exact fp32 column sums (coalesced per row)
    float acc = 0.f;
    for (int i = 0; i < 128; i++) acc += om[((size_t)(h * 128 + i)) * 128 + t];
    osum[h * 128 + t] = acc;
  }
  __syncthreads();
  { // transposed write: wt[h][j][i] = omega[h][i][j]
    int j = t >> 1, lh = (t & 1) << 6;
    s16x8* dst = (s16x8*)(wt + ((size_t)(h * 128 + j)) * 128 + lh);
    for (int u = 0; u < 8; u++) {
      s16x8 pv;
#pragma unroll
      for (int e = 0; e < 8; e++) pv[e] = (short)T[lh + u * 8 + e][j];
      dst[u] = pv;
    }
  }
}

// ---------------------- K1: K features (natural kb3 + transposed kbt3), V transposed (vt), via LDS
// kb3 b-weights {c^2, s^2, sc}. One 32-row strip per block.
__global__ __launch_bounds__(256) void k_kvfeat(const float* __restrict__ kg, const float* __restrict__ vg,
                                                const float* __restrict__ klg, const float* __restrict__ osum,
                                                u16* __restrict__ kb3, u16* __restrict__ kbt3,
                                                u16* __restrict__ vt) {
  __shared__ alignas(16) u16 Bu[4][32][136]; // Kb0,Kb1,Kb2,V strip tiles
  __shared__ float osb[128];
  int bid = blockIdx.x, t = threadIdx.x;
  int ls = bid & 63, h = (bid >> 6) & 7, n = bid >> 9;
  int l0 = ls << 5, nh = (n << 3) + h;
  const float invL = 1.0f / 2048.0f;
  if (t < 128) osb[t] = osum[h * 128 + t];
  __syncthreads();
  for (int idx = t; idx < 1024; idx += 256) {
    int rr = idx >> 5, cs = (idx & 31) << 2;
    int l = l0 + rr;
    size_t gb = (((size_t)(n * Ln + l) * 8 + h) << 7) + cs;
    f32x4 kv = *(const f32x4*)(kg + gb);
    f32x4 vv = *(const f32x4*)(vg + gb);
    float klv = klg[n * Ln + l];
    float tb = (float)l * invL;
#pragma unroll
    for (int e = 0; e < 4; e++) {
      int i = cs + e;
      float kf = (kv[e] > 0.f ? kv[e] + 1.f : __expf(kv[e])) * klv;
      float tt = tb * osb[i];
      float s, c; __sincosf(tt, &s, &c);
      Bu[0][rr][i] = f2b(kf * c * c);
      Bu[1][rr][i] = f2b(kf * s * s);
      Bu[2][rr][i] = f2b(kf * s * c);
      Bu[3][rr][i] = f2b(vv[e]);
    }
  }
  __syncthreads();
  for (int idx = t; idx < 2560; idx += 256) {
    if (idx < 1024) { // transposed stores (kbt3, vt): 32 B per item, 64 B per (arr,i)
      int arr = idx >> 8, rem = idx & 255, i = rem >> 1, hf = rem & 1;
      int lc = hf << 4;
      u16 tmp[16];
#pragma unroll
      for (int u = 0; u < 16; u++) tmp[u] = Bu[arr][lc + u][i];
      u16* dst; size_t db;
      if (arr < 3) { dst = kbt3; db = ((size_t)((arr * 32 + nh) * 128 + i)) * Ln + (l0 + lc); }
      else         { dst = vt;   db = ((size_t)(nh * 128 + i)) * Ln + (l0 + lc); }
      s16x8 p0, p1;
#pragma unroll
      for (int e = 0; e < 8; e++) { p0[e] = (short)tmp[e]; p1[e] = (short)tmp[8 + e]; }
      *(s16x8*)(dst + db) = p0;
      *(s16x8*)(dst + db + 8) = p1;
    } else {          // natural kb3 stores, vectorized
      int r2 = idx - 1024, arr = r2 >> 9, rem = r2 & 511, rr = rem >> 4, g = (rem & 15) << 3;
      s16x8 pv = *(const s16x8*)&Bu[arr][rr][g];
      *(s16x8*)(kb3 + (size_t)arr * NHLD + ((size_t)nh * Ln + l0 + rr) * 128 + g) = pv;
    }
  }
}

// ---------------- P1a: per-chunk S^T[j][i] = sum_s V[s,j]*Kb[s,i]; B staged in LDS once per block
__global__ __launch_bounds__(512, 4) void p1a(const u16* __restrict__ vtg, const u16* __restrict__ kbt3,
                                              u16* __restrict__ sct, float* __restrict__ ksum) {
  __shared__ alignas(16) u16 B[128][136]; // kbt3 chunk [i][s], later reused for S^T staging
  int bid = blockIdx.x, t = threadIdx.x;
  int c = bid & 15, h = (bid >> 4) & 7, n = (bid >> 7) & 3, b = bid >> 9;
  int l0 = c << 7, nh = (n << 3) + h, bnh = b * 32 + nh;
  int lane = t & 63, quad = lane >> 4, nl = lane & 15, w = t >> 6;
  for (int idx = t; idx < 2048; idx += 512) {
    int i = idx >> 4, cs = (idx & 15) << 3;
    *(s16x8*)&B[i][cs] = *(const s16x8*)(kbt3 + ((size_t)(bnh * 128 + i)) * Ln + l0 + cs);
  }
  __syncthreads();
  f32x4 z4 = {0.f, 0.f, 0.f, 0.f};
  f32x4 acc[8];
#pragma unroll
  for (int i = 0; i < 8; i++) acc[i] = z4;
  int arow = (w << 4) + nl; // j row, 8 waves x 16 = 128
  for (int ks = 0; ks < 4; ks++) {
    int k0 = (ks << 5) + (quad << 3);
    s16x8 av = *(const s16x8*)(vtg + ((size_t)(nh * 128 + arow)) * Ln + l0 + k0);
#pragma unroll
    for (int ct = 0; ct < 8; ct++) {
      s16x8 bv = *(const s16x8*)&B[(ct << 4) + nl][k0];
      acc[ct] = __builtin_amdgcn_mfma_f32_16x16x32_bf16(av, bv, acc[ct], 0, 0, 0);
    }
  }
  if (t < 128) { // ksum[i] = row-sum of kbt3 row i (before B is overwritten)
    float s = 0.f;
#pragma unroll 4
    for (int g = 0; g < 128; g += 8) {
      s16x8 v = *(const s16x8*)&B[t][g];
#pragma unroll
      for (int e = 0; e < 8; e++) s += b2f((u16)v[e]);
    }
    ksum[(size_t)(bnh * 16 + c) * 128 + t] = s;
  }
  __syncthreads();
  { // C-layout -> B (as S^T[j][i])
    int lbase = (w << 4) + (quad << 2);
#pragma unroll
    for (int ct = 0; ct < 8; ct++) {
      int i = (ct << 4) + nl;
#pragma unroll
      for (int r = 0; r < 4; r++) B[lbase + r][i] = f2b(acc[ct][r]);
    }
  }
  __syncthreads();
  size_t sbase = ((size_t)(bnh * 16 + c)) << 14;
  for (int idx = t; idx < 2048; idx += 512) {
    int jr = idx >> 4, g = (idx & 15) << 3;
    *(s16x8*)(sct + sbase + ((size_t)jr << 7) + g) = *(const s16x8*)&B[jr][g];
  }
}

// ---------------- P1b: in-place exclusive prefix over chunks, vectorized
__global__ __launch_bounds__(256) void p1b(u16* __restrict__ sct, float* __restrict__ ksum) {
  int bid = blockIdx.x, t = threadIdx.x;
  if (bid < 768) {
    int tid = bid * 256 + t;          // 0..196607
    int bnh = tid >> 11, rem = tid & 2047;
    size_t base = ((size_t)bnh << 18) + ((size_t)rem << 3);
    float acc[8] = {0.f, 0.f, 0.f, 0.f, 0.f, 0.f, 0.f, 0.f};
    for (int c = 0; c < 16; c++) {
      size_t a = base + ((size_t)c << 14);
      s16x8 v = *(const s16x8*)(sct + a);
      s16x8 o;
#pragma unroll
      for (int e = 0; e < 8; e++) { o[e] = (short)f2b(acc[e]); acc[e] += b2f((u16)v[e]); }
      *(s16x8*)(sct + a) = o;
    }
  } else {
    int m2 = (bid - 768) * 256 + t;   // 0..12287
    int i = m2 & 127, bnh = m2 >> 7;
    size_t base = (size_t)bnh * 2048 + i;
    float acc = 0.f;
    for (int c = 0; c < 16; c++) {
      size_t a = base + (size_t)c * 128;
      float v = ksum[a];
      ksum[a] = acc;
      acc += v;
    }
  }
}

// ---------------- K2: proj = q2 @ omega (MFMA), Q features + Z_inter fused
// qb3 b-weights {s^2, c^2, -2sc}; zint[nh][l] = sum_b <Qb[l], ksum_prefix_b[c(l)]>
__global__ __launch_bounds__(256, 2) void k_qfeat(const float* __restrict__ q2g, const float* __restrict__ qg,
                                                  const u16* __restrict__ wt, const float* __restrict__ osum,
                                                  const float* __restrict__ kspre,
                                                  u16* __restrict__ qb3, float* __restrict__ zintg) {
  __shared__ alignas(16) u16 B[128][136]; // omega^T[h]; later reused rows 0..63 for sin^2(proj)
  __shared__ float osb[128];
  int bid = blockIdx.x, t = threadIdx.x;
  int m = bid & 31, h = (bid >> 5) & 7, n = bid >> 8;
  int l0 = m << 6, c = m >> 1, nh = (n << 3) + h;
  if (t < 128) osb[t] = osum[h * 128 + t];
  for (int idx = t; idx < 2048; idx += 256) {
    int j = idx >> 4, cs = (idx & 15) << 3;
    *(s16x8*)&B[j][cs] = *(const s16x8*)(wt + ((size_t)(h * 128 + j)) * 128 + cs);
  }
  __syncthreads();
  int lane = t & 63, quad = lane >> 4, nl = lane & 15, w = t >> 6;
  f32x4 z4 = {0.f, 0.f, 0.f, 0.f};
  f32x4 acc[8];
#pragma unroll
  for (int i = 0; i < 8; i++) acc[i] = z4;
  int arow = l0 + (w << 4) + nl;
  for (int ks = 0; ks < 4; ks++) {
    int k0 = (ks << 5) + (quad << 3);
    const float* ap = q2g + (((size_t)(n * Ln + arow) * 8 + h) << 7) + k0;
    s16x8 av = pack8(*(const f32x4*)ap, *(const f32x4*)(ap + 4));
#pragma unroll
    for (int ct = 0; ct < 8; ct++) {
      s16x8 bv = *(const s16x8*)&B[(ct << 4) + nl][k0];
      acc[ct] = __builtin_amdgcn_mfma_f32_16x16x32_bf16(av, bv, acc[ct], 0, 0, 0);
    }
  }
  __syncthreads();
  { // sin^2(proj) -> B rows 0..63
    int lbase = (w << 4) + (quad << 2);
#pragma unroll
    for (int ct = 0; ct < 8; ct++) {
      int j = (ct << 4) + nl;
#pragma unroll
      for (int r = 0; r < 4; r++) {
        float sp = __sinf(acc[ct][r]);
        B[lbase + r][j] = f2b(sp * sp);
      }
    }
  }
  __syncthreads();
  const float invL = 1.0f / 2048.0f;
  for (int idx = t; idx < 1024; idx += 256) {
    int l = idx >> 4, j0 = (idx & 15) << 3, gl = l0 + l;
    s16x8 s2v = *(const s16x8*)&B[l][j0];
    const float* qp = qg + (((size_t)(n * Ln + gl) * 8 + h) << 7) + j0;
    f32x4 qa = *(const f32x4*)qp, qbv = *(const f32x4*)(qp + 4);
    size_t kbb = ((size_t)nh * 16 + c) * 128 + j0;
    f32x4 kp0a = *(const f32x4*)(kspre + kbb),           kp0b = *(const f32x4*)(kspre + kbb + 4);
    f32x4 kp1a = *(const f32x4*)(kspre + kbb + KSB),     kp1b = *(const f32x4*)(kspre + kbb + KSB + 4);
    f32x4 kp2a = *(const f32x4*)(kspre + kbb + 2 * KSB), kp2b = *(const f32x4*)(kspre + kbb + 2 * KSB + 4);
    s16x8 o0, o1, o2;
    float z = 0.f;
    float tb = (float)gl * invL;
#pragma unroll
    for (int e = 0; e < 8; e++) {
      float s2p = b2f((u16)s2v[e]);
      float qv = (e < 4) ? qa[e] : qbv[e - 4];
      float f = qv > 0.f ? qv + 1.f : __expf(qv);
      float Qt = s2p * f;
      float tt = tb * osb[j0 + e];
      float s, cc; __sincosf(tt, &s, &cc);
      float v0 = Qt * s * s, v1 = Qt * cc * cc, v2 = -2.f * Qt * s * cc;
      float k0v = (e < 4) ? kp0a[e] : kp0b[e - 4];
      float k1v = (e < 4) ? kp1a[e] : kp1b[e - 4];
      float k2v = (e < 4) ? kp2a[e] : kp2b[e - 4];
      z += v0 * k0v + v1 * k1v + v2 * k2v;
      o0[e] = (short)f2b(v0); o1[e] = (short)f2b(v1); o2[e] = (short)f2b(v2);
    }
    size_t base = ((size_t)nh * Ln + gl) * 128 + j0;
    *(s16x8*)(qb3 + base)            = o0;
    *(s16x8*)(qb3 + base + NHLD)     = o1;
    *(s16x8*)(qb3 + base + 2 * NHLD) = o2;
    z += __shfl_xor(z, 1); z += __shfl_xor(z, 2);
    z += __shfl_xor(z, 4); z += __shfl_xor(z, 8);
    if (nl == 0) zintg[(size_t)nh * Ln + gl] = z;
  }
}

// ---------------- P3: full-chunk blocks, double-tile staging (T0=Kb, T1=Sprefix^T per branch),
//                  mask + intra PV + reg Z, full-line fp32 output via LDS overlay.
__global__ __launch_bounds__(512, 4) void p3(const u16* __restrict__ qb3, const u16* __restrict__ kb3,
                                             const u16* __restrict__ vtg, const u16* __restrict__ sct,
                                             const float* __restrict__ zintg, float* __restrict__ outg) {
  __shared__ union {
    struct { alignas(16) u16 T0[128][136]; alignas(16) u16 T1[128][136]; } s;
    alignas(16) float O[128][132];
  } sm;
  int bid = blockIdx.x, t = threadIdx.x;
  int c = bid & 15, h = (bid >> 4) & 7, n = bid >> 7;
  int l0c = c << 7, nh = (n << 3) + h;
  int lane = t & 63, quad = lane >> 4, nl = lane & 15, w = t >> 6;
  f32x4 z4 = {0.f, 0.f, 0.f, 0.f};
  f32x4 accP[8], accO[8];
#pragma unroll
  for (int i = 0; i < 8; i++) { accP[i] = z4; accO[i] = z4; }
  int arow = l0c + (w << 4) + nl;
  for (int b = 0; b < 3; b++) {
    int bnh = b * 32 + nh;
    __syncthreads();
    for (int idx = t; idx < 2048; idx += 512) { // T0 <- Kb chunk [s][i]
      int s = idx >> 4, cs = (idx & 15) << 3;
      *(s16x8*)&sm.s.T0[s][cs] = *(const s16x8*)(kb3 + (((size_t)bnh * Ln + l0c + s) << 7) + cs);
    }
    size_t sbase = ((size_t)(bnh * 16 + c)) << 14;
    for (int idx = t; idx < 2048; idx += 512) { // T1 <- Sprefix^T [j][i]
      int j = idx >> 4, cs = (idx & 15) << 3;
      *(s16x8*)&sm.s.T1[j][cs] = *(const s16x8*)(sct + sbase + ((size_t)j << 7) + cs);
    }
    __syncthreads();
    s16x8 av[4];
#pragma unroll
    for (int ks = 0; ks < 4; ks++)
      av[ks] = *(const s16x8*)(qb3 + (((size_t)bnh * Ln + arow) << 7) + (ks << 5) + (quad << 3));
    for (int ks = 0; ks < 4; ks++) {
      int k0 = (ks << 5) + (quad << 3);
#pragma unroll
      for (int ct = 0; ct < 8; ct++) {
        s16x8 bv0 = *(const s16x8*)&sm.s.T0[(ct << 4) + nl][k0];
        accP[ct] = __builtin_amdgcn_mfma_f32_16x16x32_bf16(av[ks], bv0, accP[ct], 0, 0, 0);
        s16x8 bv1 = *(const s16x8*)&sm.s.T1[(ct << 4) + nl][k0];
        accO[ct] = __builtin_amdgcn_mfma_f32_16x16x32_bf16(av[ks], bv1, accO[ct], 0, 0, 0);
      }
    }
  }
  __syncthreads();
  // masked P -> T0 as P[l][s] (bf16) + register row-sums; stage T1 <- V^T [j][s]
  float zP[4] = {0.f, 0.f, 0.f, 0.f};
  int lbase = (w << 4) + (quad << 2);
#pragma unroll
  for (int ct = 0; ct < 8; ct++) {
    int ss = (ct << 4) + nl;
#pragma unroll
    for (int r = 0; r < 4; r++) {
      int lr = lbase + r;
      float pv = (ss <= lr) ? accP[ct][r] : 0.f;
      zP[r] += pv;
      sm.s.T0[lr][ss] = f2b(pv);
    }
  }
#pragma unroll
  for (int mteam = 1; mteam <= 8; mteam <<= 1) {
#pragma unroll
    for (int r = 0; r < 4; r++) zP[r] += __shfl_xor(zP[r], mteam);
  }
  for (int idx = t; idx < 2048; idx += 512) { // T1 <- V^T [j][s]
    int j = idx >> 4, cs = (idx & 15) << 3;
    *(s16x8*)&sm.s.T1[j][cs] = *(const s16x8*)(vtg + ((size_t)(nh * 128 + j)) * Ln + l0c + cs);
  }
  float zf[4];
#pragma unroll
  for (int r = 0; r < 4; r++)
    zf[r] = zintg[(size_t)nh * Ln + l0c + lbase + r] + zP[r] + 1e-6f;
  __syncthreads();
  // intra: A = masked P (T0 rows l, k=s), B = V^T (T1 rows j, k=s)
  for (int ks = 0; ks < 4; ks++) {
    int k0 = (ks << 5) + (quad << 3);
    s16x8 pav = *(const s16x8*)&sm.s.T0[(w << 4) + nl][k0];
#pragma unroll
    for (int ct = 0; ct < 8; ct++) {
      s16x8 vv = *(const s16x8*)&sm.s.T1[(ct << 4) + nl][k0];
      accO[ct] = __builtin_amdgcn_mfma_f32_16x16x32_bf16(pav, vv, accO[ct], 0, 0, 0);
    }
  }
  __syncthreads();
  // divided result -> fp32 LDS overlay (T0/T1 dead now)
#pragma unroll
  for (int ct = 0; ct < 8; ct++) {
    int j = (ct << 4) + nl;
#pragma unroll
    for (int r = 0; r < 4; r++) sm.O[lbase + r][j] = accO[ct][r] / zf[r];
  }
  __syncthreads();
  for (int idx = t; idx < 4096; idx += 512) { // full 512B-row coalesced stores
    int l = idx >> 5, g = (idx & 31) << 2;
    *(f32x4*)(outg + (((size_t)(n * Ln + l0c + l) * 8 + h) << 7) + g) = *(const f32x4*)&sm.O[l][g];
  }
}

extern "C" void kernel_launch(void* const* d_in, const int* in_sizes, int n_in,
                              void* d_out, int out_size, void* d_ws, size_t ws_size,
                              hipStream_t stream) {
  (void)in_sizes; (void)n_in; (void)out_size; (void)ws_size;
  const float* q   = (const float*)d_in[0];
  const float* q2  = (const float*)d_in[1];
  const float* kk  = (const float*)d_in[2];
  const float* vv  = (const float*)d_in[3];
  const float* kl  = (const float*)d_in[4];
  const float* om  = (const float*)d_in[5];
  float* out = (float*)d_out;

  // workspace carve (bf16 region then fp32 region) — ~219 MB
  u16* W     = (u16*)d_ws;
  u16* qb3   = W;                 // 3*NHLD
  u16* kb3   = W + 3 * NHLD;      // 3*NHLD
  u16* kbt3  = W + 6 * NHLD;      // 3*NHLD
  u16* vt    = W + 9 * NHLD;      // NHLD
  u16* sct   = W + 10 * NHLD;     // 3*NHLD (chunk sums -> exclusive prefix, in place)
  u16* wt    = W + 13 * NHLD;     // 131072 (omega^T bf16)
  float* ks  = (float*)(W + 13 * NHLD + 131072); // 196608 f32 (chunk Ksum -> prefix)
  float* osm = ks + 196608;       // 1024 f32
  float* zin = osm + 1024;        // 65536 f32 (Z_inter)

  k_omega <<<8,    256, 0, stream>>>(om, wt, osm);
  k_kvfeat<<<2048, 256, 0, stream>>>(kk, vv, kl, osm, kb3, kbt3, vt);
  p1a     <<<1536, 512, 0, stream>>>(vt, kbt3, sct, ks);
  p1b     <<<816,  256, 0, stream>>>(sct, ks);
  k_qfeat <<<1024, 256, 0, stream>>>(q2, q, wt, osm, ks, qb3, zin);
  p3      <<<512,  512, 0, stream>>>(qb3, kb3, vt, sct, zin, out);
}